// Round 5
// baseline (156.288 us; speedup 1.0000x reference)
//
#include <hip/hip_runtime.h>

#define SM 1028
#define D_ 256
#define S_ 1024
#define B_ 8

// Kernel 1: c[b,d,i] = sum_{w<i} x[b,d,w] * weight[d,i,w]; y = x*(1+relu(c))
// grid: 1024 blocks = 256 d * 4 row-blocks (256 rows). block: 256 thr = 4 waves.
// Wave owns 64 rows as 16 groups x 4 lanes; group (q,m) owns rows
// r0=wb+m+16q+{0,4,8,12} (all byte-phase 16*m since row stride 4112 B = 16 mod
// 64); chunk grid shifted by a=(16-4m)&15 so every 64 B group-span is
// line-aligned (zero straddle). NEW vs round 4: explicit 2-deep A/B parity
// pipeline -- 4-8 loads (64-128 B/lane) in flight during FMAs, and at loop
// exit A/B hold exactly the two epilogue chunks (F, F+1) so the causal tail
// is masked in-register with NO extra loads. Radix-4 shfl_xor reduction.
__global__ __launch_bounds__(256, 4)
void lie_mix_kernel(const float* __restrict__ x, const float* __restrict__ weight,
                    float* __restrict__ y) {
  int bid = blockIdx.x;
  int d = bid & 255;
  int bi = 3 - (bid >> 8);    // heavy row-blocks get low blockIdx
  int i0 = bi << 8;           // block rows: [i0, i0+256)

  __shared__ __align__(16) float xs[B_][1040];  // 16-elem zeroed pad per row

  int t = threadIdx.x;
#pragma unroll
  for (int bb = 0; bb < B_; ++bb) {
    const float4* src = (const float4*)(x + ((size_t)bb * D_ + d) * S_);
    *(float4*)&xs[bb][t << 2] = src[t];
  }
  if (t < 32)
    *(float4*)&xs[t >> 2][1024 + ((t & 3) << 2)] = make_float4(0.f, 0.f, 0.f, 0.f);
  __syncthreads();

  int lane = t & 63;
  int wid = t >> 6;
  int wb = i0 + (wid << 6);          // wave rows: [wb, wb+64)
  int g = lane >> 2;                 // 16 groups of 4 lanes
  int j = lane & 3;                  // lane within group
  int m = g & 3;                     // phase class (rows == m mod 4)
  int q = g >> 2;
  int r0 = wb + m + (q << 4);        // lane's rows: r0 + 4k, k=0..3
  int a = (16 - (m << 2)) & 15;      // aligned chunk-grid shift (elements)

  const float* wptr = weight + ((size_t)d * SM + r0) * SM + a + (j << 2);

  float acc[4][8];
#pragma unroll
  for (int k = 0; k < 4; ++k)
#pragma unroll
    for (int b = 0; b < 8; ++b) acc[k][b] = 0.f;

#define LOADW(buf, c)                                                    \
  do {                                                                   \
    int _w0 = (c) << 4;                                                  \
    _Pragma("unroll") for (int k = 0; k < 4; ++k)                        \
        buf[k] = *(const float4*)(wptr + (size_t)(k * 4) * SM + _w0);    \
  } while (0)

#define FMA_CHUNK(buf, c)                                                \
  do {                                                                   \
    int _e = a + ((c) << 4) + (j << 2);                                  \
    _Pragma("unroll") for (int b = 0; b < 8; ++b) {                      \
      float4 xb = *(const float4*)&xs[b][_e];                            \
      _Pragma("unroll") for (int k = 0; k < 4; ++k) {                    \
        acc[k][b] += xb.x * buf[k].x + xb.y * buf[k].y +                 \
                     xb.z * buf[k].z + xb.w * buf[k].w;                  \
      }                                                                  \
    }                                                                    \
  } while (0)

  // masked tail FMA using ALREADY-LOADED buffer (chunk cX in registers)
#define EPI(buf, cX)                                                     \
  do {                                                                   \
    int _w0 = (cX) << 4;                                                 \
    int _es = a + _w0 + (j << 2);                                        \
    int _ex = _es > 1024 ? 1024 : _es; /* clamp into zeroed pad */       \
    _Pragma("unroll") for (int k = 0; k < 4; ++k) {                      \
      int rk = r0 + (k << 2);                                            \
      if (_es >= rk) buf[k].x = 0.f;                                     \
      if (_es + 1 >= rk) buf[k].y = 0.f;                                 \
      if (_es + 2 >= rk) buf[k].z = 0.f;                                 \
      if (_es + 3 >= rk) buf[k].w = 0.f;                                 \
    }                                                                    \
    _Pragma("unroll") for (int b = 0; b < 8; ++b) {                      \
      float4 xb = *(const float4*)&xs[b][_ex];                           \
      _Pragma("unroll") for (int k = 0; k < 4; ++k) {                    \
        acc[k][b] += xb.x * buf[k].x + xb.y * buf[k].y +                 \
                     xb.z * buf[k].z + xb.w * buf[k].w;                  \
      }                                                                  \
    }                                                                    \
  } while (0)

  // ---- prologue: elements [0, a), line-aligned window [a-16, a) ----
  if (a > 0) {
    int e_s = a - 16 + (j << 2);
    if (e_s >= 0) {                  // float4 fully within [0, a)
      float4 xb[8];
#pragma unroll
      for (int b = 0; b < 8; ++b) xb[b] = *(const float4*)&xs[b][e_s];
#pragma unroll
      for (int k = 0; k < 4; ++k) {
        int rk = r0 + (k << 2);
        float4 v = make_float4(0.f, 0.f, 0.f, 0.f);
        if (e_s < rk) v = *(const float4*)(wptr - 16 + (size_t)(k * 4) * SM);
        if (e_s + 1 >= rk) v.y = 0.f;
        if (e_s + 2 >= rk) v.z = 0.f;
        if (e_s + 3 >= rk) v.w = 0.f;
#pragma unroll
        for (int b = 0; b < 8; ++b)
          acc[k][b] += xb[b].x * v.x + xb[b].y * v.y + xb[b].z * v.z + xb[b].w * v.w;
      }
    }
  }

  // ---- pipelined main loop over full 16-elem chunks ----
  int F = (r0 - a) >> 4;             // per-lane full-chunk count
  if (F < 0) F = 0;

  float4 bufA[4], bufB[4];
  LOADW(bufA, 0);                    // safe: in-bounds even past triangle
  LOADW(bufB, 1);

  for (int c = 0; c < F; c += 2) {
    FMA_CHUNK(bufA, c);
    LOADW(bufA, c + 2);
    if (c + 1 < F) {
      FMA_CHUNK(bufB, c + 1);
      LOADW(bufB, c + 3);
    }
  }

  // A holds chunk F+(F&1), B holds chunk F+1-(F&1) (per lane, via exec mask)
  EPI(bufA, F + (F & 1));
  EPI(bufB, F + 1 - (F & 1));

  // ---- reduce across the 4 lanes of each group (xor 1,2 stay in-group) ----
#pragma unroll
  for (int s = 1; s < 4; s <<= 1)
#pragma unroll
    for (int k = 0; k < 4; ++k)
#pragma unroll
      for (int b = 0; b < 8; ++b)
        acc[k][b] += __shfl_xor(acc[k][b], s, 64);

  // lane j writes batches j and j+4 for its 4 (strided) rows
  {
    int b0 = j, b1 = j + 4;
#pragma unroll
    for (int k = 0; k < 4; ++k) {
      int r = r0 + (k << 2);
      float x0 = xs[b0][r], x1 = xs[b1][r];
      y[((size_t)b0 * D_ + d) * S_ + r] = x0 * (1.f + fmaxf(acc[k][b0], 0.f));
      y[((size_t)b1 * D_ + d) * S_ + r] = x1 * (1.f + fmaxf(acc[k][b1], 0.f));
    }
  }
#undef LOADW
#undef FMA_CHUNK
#undef EPI
}

// Kernel 2: LayerNorm over channel axis d (size 256) per (b, s).
__global__ __launch_bounds__(256)
void ln_kernel(const float* __restrict__ y, const float* __restrict__ gamma,
               const float* __restrict__ beta, float* __restrict__ out) {
  __shared__ float tile[D_][33];
  __shared__ float ps[8][32];
  __shared__ float pq[8][32];
  __shared__ float mu[32];
  __shared__ float rs[32];
  int b = blockIdx.x >> 5;
  int s0 = (blockIdx.x & 31) << 5;
  int t = threadIdx.x;
  int sj = t & 31, dq = t >> 5;
  for (int dd = dq; dd < D_; dd += 8)
    tile[dd][sj] = y[((size_t)b * D_ + dd) * S_ + s0 + sj];
  __syncthreads();
  float sm = 0.f, sq = 0.f;
#pragma unroll 8
  for (int r = 0; r < 32; ++r) {
    float v = tile[dq * 32 + r][sj];
    sm += v;
    sq += v * v;
  }
  ps[dq][sj] = sm;
  pq[dq][sj] = sq;
  __syncthreads();
  if (t < 32) {
    float S = 0.f, Q = 0.f;
#pragma unroll
    for (int qq = 0; qq < 8; ++qq) { S += ps[qq][t]; Q += pq[qq][t]; }
    float mm = S * (1.f / 256.f);
    float var = Q * (1.f / 256.f) - mm * mm;
    mu[t] = mm;
    rs[t] = rsqrtf(var + 1e-5f);
  }
  __syncthreads();
  for (int dd = dq; dd < D_; dd += 8) {
    float v = tile[dd][sj];
    out[((size_t)b * D_ + dd) * S_ + s0 + sj] =
        (v - mu[sj]) * rs[sj] * gamma[dd] + beta[dd];
  }
}

extern "C" void kernel_launch(void* const* d_in, const int* in_sizes, int n_in,
                              void* d_out, int out_size, void* d_ws, size_t ws_size,
                              hipStream_t stream) {
  const float* x = (const float*)d_in[0];
  const float* weight = (const float*)d_in[1];
  const float* gamma = (const float*)d_in[2];
  const float* beta = (const float*)d_in[3];
  float* out = (float*)d_out;
  float* y = (float*)d_ws;  // 8*256*1024 f32 = 8 MB scratch

  lie_mix_kernel<<<1024, 256, 0, stream>>>(x, weight, y);
  ln_kernel<<<256, 256, 0, stream>>>(y, gamma, beta, out);
}